// Round 12
// baseline (326.837 us; speedup 1.0000x reference)
//
#include <hip/hip_runtime.h>
#include <math.h>

#define N_NODES 100000
#define N_EDGES 1600000
#define F 128

// CSR radix: buckets of 256 destination nodes, fixed-capacity segments
#define BSH 8
#define NBUCK 391          // ceil(100000 / 256)
#define BCAP 5120          // per-bucket capacity (mean 4096, +16 sigma)
#define PB_EDGES 2048      // edges per part block
#define NB_PART 782        // part blocks (ceil(1.6M/2048)) -- dispatched FIRST
#define NB_SCORES 1563     // score blocks (64 nodes/block, 16 nodes/wave)

typedef unsigned int u32;
typedef unsigned short u16;
typedef __attribute__((ext_vector_type(8))) short short8;
typedef __attribute__((ext_vector_type(4))) float floatx4;
typedef __attribute__((ext_vector_type(2))) float f32x2;

// ---------------- helpers ----------------

__device__ __forceinline__ u32 key_of(float s) {
    u32 u = __float_as_uint(s);
    return (u & 0x80000000u) ? ~u : (u | 0x80000000u);   // larger float -> larger key
}

__device__ __forceinline__ float wave_reduce(float v) {
    #pragma unroll
    for (int off = 32; off > 0; off >>= 1) v += __shfl_down(v, off, 64);
    return v;
}

__device__ __forceinline__ u16 f2bf(float f) {   // round-to-nearest-even
    u32 u = __float_as_uint(f);
    u += 0x7fffu + ((u >> 16) & 1u);
    return (u16)(u >> 16);
}

__device__ __forceinline__ float bflo(u32 b) { return __uint_as_float(b << 16); }
__device__ __forceinline__ float bfhi(u32 b) { return __uint_as_float(b & 0xffff0000u); }

// packed fp32 accumulate: acc.{x,y} += {lo,hi bf16 of u}
__device__ __forceinline__ void pk_acc(f32x2& acc, u32 u) {
    f32x2 v; v.x = bflo(u); v.y = bfhi(u);
    asm("v_pk_add_f32 %0, %1, %0" : "+v"(acc) : "v"(v));
}
__device__ __forceinline__ void pk_add2(f32x2& a, f32x2 b) {
    asm("v_pk_add_f32 %0, %1, %0" : "+v"(a) : "v"(b));
}

// ---------------- 1. fused front: edge partition (first) | scores -----------------
// Score branch is now a PURE stream: no hist16 atomics (they were ~100k RMWs
// concentrated on a few hundred hot L2 lines -- the invariant ~60us), no xb.

__global__ void k_front(const float* __restrict__ x, const float* __restrict__ p,
                        const int* __restrict__ ei, float* __restrict__ scores,
                        u32* __restrict__ gcur, u32* __restrict__ pairs) {
    if (blockIdx.x < NB_PART) {
        // ---- radix partition of edges into 256-node destination buckets
        __shared__ u32 lh[NBUCK];     // local histogram, then local cursor
        __shared__ u32 lbase[NBUCK];  // reserved base within bucket segment
        int t = threadIdx.x;
        int e0 = blockIdx.x * PB_EDGES;
        int e1 = e0 + PB_EDGES; if (e1 > N_EDGES) e1 = N_EDGES;
        for (int i = t; i < NBUCK; i += 256) lh[i] = 0u;
        __syncthreads();
        for (int e = e0 + t; e < e1; e += 256)
            atomicAdd(&lh[((u32)ei[N_EDGES + e]) >> BSH], 1u);
        __syncthreads();
        for (int b = t; b < NBUCK; b += 256) {
            u32 c = lh[b];
            lbase[b] = c ? atomicAdd(&gcur[b], c) : 0u;
            lh[b] = 0u;
        }
        __syncthreads();
        for (int e = e0 + t; e < e1; e += 256) {
            u32 d = (u32)ei[N_EDGES + e];
            u32 b = d >> BSH;
            u32 pos = lbase[b] + atomicAdd(&lh[b], 1u);
            pairs[(size_t)b * BCAP + pos] = ((d & 255u) << 17) | (u32)ei[e];
        }
    } else {
        // ---- scores: 16 nodes per wave (16 lanes per node, 4 rounds)
        int sb = blockIdx.x - NB_PART;
        int wave = threadIdx.x >> 6;
        int lane = threadIdx.x & 63;
        int q = lane >> 4, sub = lane & 15;
        int nb0 = sb * 64 + wave * 16 + q;      // node for round r: nb0 + r*4
        float4 p0 = *(const float4*)&p[sub * 8];
        float4 p1 = *(const float4*)&p[sub * 8 + 4];
        #pragma unroll
        for (int r = 0; r < 4; r++) {
            int node = nb0 + r * 4;
            if (node >= N_NODES) continue;
            const float* xr = &x[(size_t)node * F + sub * 8];
            float4 v0 = *(const float4*)xr;
            float4 v1 = *(const float4*)(xr + 4);
            float d = v0.x * p0.x + v0.y * p0.y + v0.z * p0.z + v0.w * p0.w
                    + v1.x * p1.x + v1.y * p1.y + v1.z * p1.z + v1.w * p1.w;
            #pragma unroll
            for (int off = 1; off < 16; off <<= 1) d += __shfl_xor(d, off, 64);
            if (sub == 0) scores[node] = d;
        }
    }
}

// ---------------- 2. k_select: exact top-128 (block 0) | bbase scan (block 1) ------
// All-LDS selection: 4096-bin histogram on key>>20, refine at key>>8 within the
// crossing bucket, collect candidates, exact rank. Zero global atomics.

__global__ __launch_bounds__(1024) void k_select(const float* __restrict__ scores,
                                                 const float* __restrict__ p,
                                                 u32* __restrict__ top_idx,
                                                 float* __restrict__ gate,
                                                 const u32* __restrict__ gcur,
                                                 u32* __restrict__ bbase) {
    int t = threadIdx.x;
    if (blockIdx.x == 1) {
        // ---- exclusive prefix scan of gcur -> bbase
        __shared__ u32 a[1024];
        u32 v = (t < NBUCK) ? gcur[t] : 0u;
        a[t] = v;
        __syncthreads();
        for (int off = 1; off < 1024; off <<= 1) {
            u32 add = (t >= off) ? a[t - off] : 0u;
            __syncthreads();
            a[t] += add;
            __syncthreads();
        }
        if (t < NBUCK) bbase[t] = a[t] - v;
        return;
    }
    __shared__ u32 hist[4096];
    __shared__ u32 s1[1024];
    __shared__ u32 ci[2048];
    __shared__ float csc[2048];
    __shared__ float s_inv;
    __shared__ u32 sb1, sabove1, st24, scnt;
    if (t < 64) {
        float2 pv = *(const float2*)&p[t * 2];
        float d = pv.x * pv.x + pv.y * pv.y;
        d = wave_reduce(d);
        if (t == 0) s_inv = rsqrtf(d);
    }
    if (t == 0) scnt = 0u;
    #pragma unroll
    for (int i = 0; i < 4; i++) hist[t * 4 + i] = 0u;
    __syncthreads();
    // P1: histogram key>>20 (LDS atomics only)
    for (int i = t; i < N_NODES; i += 1024)
        atomicAdd(&hist[key_of(scores[i]) >> 20], 1u);
    __syncthreads();
    s1[t] = hist[4 * t] + hist[4 * t + 1] + hist[4 * t + 2] + hist[4 * t + 3];
    __syncthreads();
    for (int off = 1; off < 1024; off <<= 1) {       // suffix sums
        u32 add = (t + off < 1024) ? s1[t + off] : 0u;
        __syncthreads();
        s1[t] += add;
        __syncthreads();
    }
    {
        u32 above = (t == 1023) ? 0u : s1[t + 1];
        if (above < 128u && s1[t] >= 128u) {          // crossing group
            u32 run = above;
            for (int bin = 4 * t + 3; bin >= 4 * t; bin--) {
                if (run + hist[bin] >= 128u) { sb1 = (u32)bin; sabove1 = run; break; }
                run += hist[bin];
            }
        }
    }
    __syncthreads();
    u32 b1 = sb1, above1 = sabove1;
    // P2: refine inside bucket b1 at (key>>8)&0xfff granularity
    #pragma unroll
    for (int i = 0; i < 4; i++) hist[t * 4 + i] = 0u;
    __syncthreads();
    for (int i = t; i < N_NODES; i += 1024) {
        u32 k = key_of(scores[i]);
        if ((k >> 20) == b1) atomicAdd(&hist[(k >> 8) & 0xfffu], 1u);
    }
    __syncthreads();
    s1[t] = hist[4 * t] + hist[4 * t + 1] + hist[4 * t + 2] + hist[4 * t + 3];
    __syncthreads();
    for (int off = 1; off < 1024; off <<= 1) {
        u32 add = (t + off < 1024) ? s1[t + off] : 0u;
        __syncthreads();
        s1[t] += add;
        __syncthreads();
    }
    {
        u32 above = above1 + ((t == 1023) ? 0u : s1[t + 1]);
        if (above < 128u && above1 + s1[t] >= 128u) { // crossing group
            u32 run = above;
            for (int bin = 4 * t + 3; bin >= 4 * t; bin--) {
                if (run + hist[bin] >= 128u) {
                    st24 = (b1 << 12) | (u32)bin;     // 24-bit threshold prefix
                    break;
                }
                run += hist[bin];
            }
        }
    }
    __syncthreads();
    u32 t24 = st24;
    // P3: collect candidates (key>>8 >= t24) -- guaranteed >= 128, typically ~150
    for (int i = t; i < N_NODES; i += 1024) {
        u32 k = key_of(scores[i]);
        if ((k >> 8) >= t24) {
            u32 pos = atomicAdd(&scnt, 1u);
            if (pos < 2048u) { ci[pos] = (u32)i; csc[pos] = scores[i]; }
        }
    }
    __syncthreads();
    u32 nc = scnt; if (nc > 2048u) nc = 2048u;
    for (u32 i = t; i < nc; i += 1024) {
        u32 myk = key_of(csc[i]);
        u32 myi = ci[i];
        int rank = 0;
        for (u32 j = 0; j < nc; j++) {
            u32 ok = key_of(csc[j]);
            rank += (int)((ok > myk) || (ok == myk && ci[j] < myi));
        }
        if (rank < 128) {   // exact jax semantics: value desc, index asc on ties
            top_idx[rank] = myi;
            gate[rank] = tanhf(csc[i] * s_inv);
        }
    }
}

// ---------------- 2b. CSR finalize (pure, 391 blocks) ------------------------------

__global__ __launch_bounds__(256) void k_mid(const u32* __restrict__ pairs,
                                             const u32* __restrict__ gcur,
                                             const u32* __restrict__ bbase,
                                             u32* __restrict__ offs,
                                             float* __restrict__ dinv,
                                             u32* __restrict__ ebuf) {
    __shared__ u32 h[256];
    __shared__ u32 sc[256];
    int b = blockIdx.x, t = threadIdx.x;
    u32 base = bbase[b];
    u32 cnt  = gcur[b];
    const u32* seg = pairs + (size_t)b * BCAP;
    u32 lo = (u32)b << BSH;
    h[t] = 0u;
    __syncthreads();
    for (u32 i = t; i < cnt; i += 256)
        atomicAdd(&h[seg[i] >> 17], 1u);
    __syncthreads();
    sc[t] = h[t];
    __syncthreads();
    for (int off = 1; off < 256; off <<= 1) {
        u32 v = (t >= off) ? sc[t - off] : 0u;
        __syncthreads();
        sc[t] += v;
        __syncthreads();
    }
    int nn = N_NODES - (int)lo;     // >=256 except last bucket (160)
    if (t < nn) {
        u32 c = h[t];
        offs[lo + t] = base + (sc[t] - c);
        dinv[lo + t] = rsqrtf((float)c + 1.0f);
    }
    u32 excl = sc[t] - h[t];
    __syncthreads();
    sc[t] = excl;
    __syncthreads();
    for (u32 i = t; i < cnt; i += 256) {
        u32 pr = seg[i];
        u32 pos = base + atomicAdd(&sc[pr >> 17], 1u);
        ebuf[pos] = pr & 0x1ffffu;
    }
    if (b == 0 && t == 0) offs[N_NODES] = N_EDGES;
}

// ---------------- 3a. GRU GEMMs: g[128][768] = [x_tilde | W] . [w_ih | w_hh]^T -----

__global__ __launch_bounds__(256) void k_ggemm(const float* __restrict__ x,
                                               const float* __restrict__ W,
                                               const float* __restrict__ w_ih,
                                               const float* __restrict__ w_hh,
                                               const u32* __restrict__ top_idx,
                                               const float* __restrict__ gate,
                                               float* __restrict__ G) {
    __shared__ float As[32][128];
    __shared__ float Bs[64][131];
    int t = threadIdx.x;
    int k0 = blockIdx.x * 32;
    int by = blockIdx.y;                // 0..11; <6 -> gi (w_ih, x_tilde), else gh
    int j0 = by * 64;
    bool is_gi = (by < 6);
    #pragma unroll
    for (int i = 0; i < 4; i++) {
        int l = t + i * 256;
        int row = l >> 5, c4 = l & 31;
        float4 v;
        if (is_gi) {
            u32 idx = top_idx[k0 + row];
            float gt = gate[k0 + row];
            v = *(const float4*)&x[(size_t)idx * F + c4 * 4];
            v.x *= gt; v.y *= gt; v.z *= gt; v.w *= gt;
        } else {
            v = *(const float4*)&W[(k0 + row) * F + c4 * 4];
        }
        *(float4*)&As[row][c4 * 4] = v;
    }
    const float* mat = is_gi ? w_ih : w_hh;
    int jbase = is_gi ? j0 : (j0 - 384);
    #pragma unroll
    for (int i = 0; i < 8; i++) {
        int l = t + i * 256;
        int row = l >> 5, c4 = l & 31;
        float4 v = *(const float4*)&mat[(jbase + row) * F + c4 * 4];
        Bs[row][c4 * 4 + 0] = v.x; Bs[row][c4 * 4 + 1] = v.y;
        Bs[row][c4 * 4 + 2] = v.z; Bs[row][c4 * 4 + 3] = v.w;
    }
    __syncthreads();
    int ty = t >> 5, tx = t & 31;
    float acc[4][2] = {};
    #pragma unroll 4
    for (int f = 0; f < 128; f++) {
        float b0 = Bs[tx * 2][f], b1 = Bs[tx * 2 + 1][f];
        #pragma unroll
        for (int i = 0; i < 4; i++) {
            float a = As[ty * 4 + i][f];
            acc[i][0] += a * b0;
            acc[i][1] += a * b1;
        }
    }
    #pragma unroll
    for (int i = 0; i < 4; i++) {
        int k = k0 + ty * 4 + i;
        G[(size_t)k * 768 + j0 + tx * 2 + 0] = acc[i][0];
        G[(size_t)k * 768 + j0 + tx * 2 + 1] = acc[i][1];
    }
}

// ---------------- 3b. pointwise GRU gates -> Wnew + fragment-ordered bf16 B --------

__global__ void k_gate(const float* __restrict__ G, const float* __restrict__ W,
                       const float* __restrict__ b_ih, const float* __restrict__ b_hh,
                       float* __restrict__ Wnew, u16* __restrict__ Bfrag) {
    int idx = blockIdx.x * blockDim.x + threadIdx.x;   // 16384
    int k = idx >> 7, h = idx & 127;
    const float* gk = &G[(size_t)k * 768];
    float gir = gk[h]       + b_ih[h];
    float giz = gk[128 + h] + b_ih[128 + h];
    float gin = gk[256 + h] + b_ih[256 + h];
    float ghr = gk[384 + h] + b_hh[h];
    float ghz = gk[512 + h] + b_hh[128 + h];
    float ghn = gk[640 + h] + b_hh[256 + h];
    float wv  = W[k * F + h];
    float rg = 1.0f / (1.0f + expf(-(gir + ghr)));
    float z  = 1.0f / (1.0f + expf(-(giz + ghz)));
    float n  = tanhf(gin + rg * ghn);
    float val = (1.0f - z) * n + z * wv;
    Wnew[k * F + h] = val;
    int nb = h >> 4, kc = k >> 5, q = (k >> 3) & 3, m = h & 15, jj = k & 7;
    Bfrag[(((nb * 4 + kc) * 64) + q * 16 + m) * 8 + jj] = f2bf(val);
}

// ---------------- 5. yw = dinv * (x @ W_new) : bf16 MFMA ---------------------------
// fp32-staging path (round-0 proven). MFMA + LDS-transposed coalesced epilogue.

__global__ __launch_bounds__(256) void k_gemm(const float* __restrict__ x,
                                              const u16* __restrict__ Bfrag,
                                              const float* __restrict__ dinv,
                                              u16* __restrict__ yw) {
    __shared__ __align__(16) u16 As[8448];
    int t = threadIdx.x;
    int r0 = blockIdx.x * 64;
    #pragma unroll
    for (int i = 0; i < 8; i++) {
        int l = t + i * 256;              // 2048 float4s
        int row = l >> 5, c4 = l & 31;
        int f0 = c4 * 4;
        float4 v = {0.f, 0.f, 0.f, 0.f};
        if (r0 + row < N_NODES) v = *(const float4*)&x[(size_t)(r0 + row) * F + f0];
        int widx = (((row >> 4) * 4 + (f0 >> 5)) * 64 + ((f0 >> 3) & 3) * 16 + (row & 15)) * 8
                   + (f0 & 7);
        ushort4 s4;
        s4.x = f2bf(v.x); s4.y = f2bf(v.y); s4.z = f2bf(v.z); s4.w = f2bf(v.w);
        *(ushort4*)&As[widx] = s4;
    }
    __syncthreads();

    int wv = t >> 6, lane = t & 63;
    int q = lane >> 4, m = lane & 15;
    floatx4 acc[8] = {};
    #pragma unroll
    for (int kc = 0; kc < 4; kc++) {
        short8 a = *(const short8*)&As[((wv * 4 + kc) * 64 + lane) * 8];
        #pragma unroll
        for (int nb = 0; nb < 8; nb++) {
            short8 bfr = *(const short8*)&Bfrag[((nb * 4 + kc) * 64 + lane) * 8];
            acc[nb] = __builtin_amdgcn_mfma_f32_16x16x32_bf16(a, bfr, acc[nb], 0, 0, 0);
        }
    }
    __syncthreads();   // done reading A-frags; reuse As as epilogue buffer

    float d[4];
    #pragma unroll
    for (int reg = 0; reg < 4; reg++) {
        int gr = r0 + wv * 16 + q * 4 + reg;
        d[reg] = (gr < N_NODES) ? dinv[gr] : 0.f;
    }
    #pragma unroll
    for (int nb = 0; nb < 8; nb++) {
        #pragma unroll
        for (int reg = 0; reg < 4; reg++) {
            int row = wv * 16 + q * 4 + reg;
            As[row * 132 + nb * 16 + m] = f2bf(acc[nb][reg] * d[reg]);
        }
    }
    __syncthreads();
    // coalesced store: thread t -> row t>>2, 32-col segment (t&3)*32 (64 B)
    {
        int row = t >> 2, segi = t & 3;
        int gr = r0 + row;
        if (gr < N_NODES) {
            const uint2* src = (const uint2*)&As[row * 132 + segi * 32];
            uint2* dst = (uint2*)&yw[(size_t)gr * F + segi * 32];
            #pragma unroll
            for (int i = 0; i < 8; i++) dst[i] = src[i];
        }
    }
}

// ---------------- 6. gather-aggregate + fused head (pre-scaled yw rows) -----------

#define EDGE_GROUP(J) {                                                      \
    u32 r = ebuf[(J) + q];                                                   \
    uint4 bb = *(const uint4*)&yw32[(size_t)r * 64 + sub * 4];               \
    pk_acc(a01, bb.x); pk_acc(a23, bb.y);                                    \
    pk_acc(a45, bb.z); pk_acc(a67, bb.w); }

#define BFLY(A) {                                                            \
    f32x2 tb;                                                                \
    tb.x = __shfl_xor(A.x, 16, 64); tb.y = __shfl_xor(A.y, 16, 64);          \
    pk_add2(A, tb);                                                          \
    tb.x = __shfl_xor(A.x, 32, 64); tb.y = __shfl_xor(A.y, 32, 64);          \
    pk_add2(A, tb); }

__global__ void k_gather(const u32* __restrict__ yw32, const u32* __restrict__ offs,
                         const u32* __restrict__ ebuf, const float* __restrict__ dinv,
                         const float* __restrict__ conv_bias, const float* __restrict__ lin_w,
                         const float* __restrict__ lin_b, float* __restrict__ out) {
    int c = blockIdx.x * 4 + (threadIdx.x >> 6);
    if (c >= N_NODES) return;
    int lane = threadIdx.x & 63;
    int q = lane >> 4, sub = lane & 15;
    u32 jbeg = offs[c], jend = offs[c + 1];
    f32x2 a01 = {0.f, 0.f}, a23 = {0.f, 0.f}, a45 = {0.f, 0.f}, a67 = {0.f, 0.f};
    u32 j = jbeg;
    for (; j + 16 <= jend; j += 16) {   // 16 edges (4 quad-groups) in flight
        EDGE_GROUP(j) EDGE_GROUP(j + 4) EDGE_GROUP(j + 8) EDGE_GROUP(j + 12)
    }
    for (; j + 4 <= jend; j += 4) EDGE_GROUP(j)
    u32 rem = jend - j;
    if (rem) {                           // 1..3 leftover edges, exec-masked adds
        u32 idx = ((u32)q < rem) ? (j + q) : j;
        u32 r = ebuf[idx];
        uint4 bb = *(const uint4*)&yw32[(size_t)r * 64 + sub * 4];
        if ((u32)q < rem) {
            pk_acc(a01, bb.x); pk_acc(a23, bb.y);
            pk_acc(a45, bb.z); pk_acc(a67, bb.w);
        }
    }
    BFLY(a01) BFLY(a23) BFLY(a45) BFLY(a67)
    float dc = dinv[c];
    uint4 sb = *(const uint4*)&yw32[(size_t)c * 64 + sub * 4];
    float4 cb0 = *(const float4*)&conv_bias[sub * 8];
    float4 cb1 = *(const float4*)&conv_bias[sub * 8 + 4];
    float4 lw0 = *(const float4*)&lin_w[sub * 8];
    float4 lw1 = *(const float4*)&lin_w[sub * 8 + 4];
    float h0 = fmaxf(dc * (a01.x + bflo(sb.x)) + cb0.x, 0.f);
    float h1 = fmaxf(dc * (a01.y + bfhi(sb.x)) + cb0.y, 0.f);
    float h2 = fmaxf(dc * (a23.x + bflo(sb.y)) + cb0.z, 0.f);
    float h3 = fmaxf(dc * (a23.y + bfhi(sb.y)) + cb0.w, 0.f);
    float h4 = fmaxf(dc * (a45.x + bflo(sb.z)) + cb1.x, 0.f);
    float h5 = fmaxf(dc * (a45.y + bfhi(sb.z)) + cb1.y, 0.f);
    float h6 = fmaxf(dc * (a67.x + bflo(sb.w)) + cb1.z, 0.f);
    float h7 = fmaxf(dc * (a67.y + bfhi(sb.w)) + cb1.w, 0.f);
    float part = (h0 * lw0.x + h1 * lw0.y + h2 * lw0.z + h3 * lw0.w)
               + (h4 * lw1.x + h5 * lw1.y + h6 * lw1.z + h7 * lw1.w);
    #pragma unroll
    for (int off = 8; off > 0; off >>= 1) part += __shfl_down(part, off, 64);
    if (lane == 0) out[c] = part + lin_b[0];
}

// ---------------- launch ----------------

extern "C" void kernel_launch(void* const* d_in, const int* in_sizes, int n_in,
                              void* d_out, int out_size, void* d_ws, size_t ws_size,
                              hipStream_t stream) {
    const float* x         = (const float*)d_in[0];
    const int*   ei        = (const int*)  d_in[1];
    const float* W         = (const float*)d_in[2];
    const float* p         = (const float*)d_in[3];
    const float* w_ih      = (const float*)d_in[4];
    const float* w_hh      = (const float*)d_in[5];
    const float* b_ih      = (const float*)d_in[6];
    const float* b_hh      = (const float*)d_in[7];
    const float* conv_bias = (const float*)d_in[8];
    const float* lin_w     = (const float*)d_in[9];
    const float* lin_b     = (const float*)d_in[10];
    float* out = (float*)d_out;

    u32*   w  = (u32*)d_ws;
    float* wf = (float*)d_ws;

    // ws layout (word offsets). G overlays PAIRS (pairs dead after k_mid).
    const size_t SCORES_W = 0;          // 100000
    const size_t DINV_W   = 100096;     // 100000
    const size_t OFFS_W   = 200192;     // 100001
    const size_t GCUR_W   = 300288;     // 391 (memset target)
    const size_t BBASE_W  = 300684;     // 391
    const size_t TOPI_W   = 301080;     // 128
    const size_t GATE_W   = 301208;     // 128
    const size_t WNEW_W   = 301336;     // 16384
    const size_t BFRAG_W  = 317720;     // 4096 words (8192 u16)
    const size_t PAIRS_W  = 321816;     // 391 * 5120 = 2001920 words
    const size_t EBUF_W   = 2400000;    // 1600000
    const size_t YW_W     = 4000000;    // bf16 yw: 6400000 words

    float* scores  = wf + SCORES_W;
    float* dinv    = wf + DINV_W;
    u32*   offs    = w  + OFFS_W;
    u32*   gcur    = w  + GCUR_W;
    u32*   bbase   = w  + BBASE_W;
    u32*   top_idx = w  + TOPI_W;
    float* gate    = wf + GATE_W;
    float* Wnew    = wf + WNEW_W;
    u16*   Bfrag   = (u16*)(w + BFRAG_W);
    u32*   pairs   = w  + PAIRS_W;
    float* G       = wf + PAIRS_W;      // overlay (pairs dead after k_mid)
    u32*   ebuf    = w  + EBUF_W;
    u16*   yw      = (u16*)(w + YW_W);
    u32*   yw32    = w + YW_W;

    hipMemsetAsync(gcur, 0, NBUCK * sizeof(u32), stream);

    // --- L1: edge partition (leads grid, overlaps) | scores (pure stream)
    k_front<<<NB_PART + NB_SCORES, 256, 0, stream>>>(x, p, ei, scores, gcur, pairs);
    // --- L2: exact top-128 (all-LDS) | gcur prefix scan -> bbase
    k_select<<<2, 1024, 0, stream>>>(scores, p, top_idx, gate, gcur, bbase);
    // --- L3: CSR finalize
    k_mid<<<NBUCK, 256, 0, stream>>>(pairs, gcur, bbase, offs, dinv, ebuf);
    // --- GRU -> W_new (bf16 fragment-packed)
    k_ggemm<<<dim3(4, 12), 256, 0, stream>>>(x, W, w_ih, w_hh, top_idx, gate, G);
    k_gate<<<64, 256, 0, stream>>>(G, W, b_ih, b_hh, Wnew, Bfrag);

    // --- yw = dinv * (x @ W_new)  (bf16 MFMA, fp32 staging)
    k_gemm<<<1563, 256, 0, stream>>>(x, Bfrag, dinv, yw);

    // --- gather + fused head
    k_gather<<<25000, 256, 0, stream>>>(yw32, offs, ebuf, dinv, conv_bias, lin_w,
                                        lin_b, out);
}